// Round 1
// baseline (5091.252 us; speedup 1.0000x reference)
//
#include <hip/hip_runtime.h>

typedef unsigned int uint;
typedef unsigned short ushort;
typedef short bf16x8 __attribute__((ext_vector_type(8)));
typedef float f32x4 __attribute__((ext_vector_type(4)));

// ---------------- dropout PRNG variant ----------------
// 2 = partitionable (counter (0,i)), bits = x0^x1   [JAX >= 0.4.30 default]
// 1 = partitionable, bits = x0
// 0 = legacy split-halves iota scheme
#define DROP_VARIANT 2

// ---------------- workspace layout (bytes) ----------------
#define XW_OFF   0ull                        // ushort [2][64][1024][1024]  (dir,b,col,t) bf16
#define XB_OFF   (XW_OFF + 268435456ull)     // ushort [64*1024*256] x in bf16
#define WT_OFF   (XB_OFF + 33554432ull)      // ushort [2][1024][256]  W^T bf16
#define UT_OFF   (WT_OFF + 1048576ull)       // ushort [2][1024][256]  U^T bf16
#define HB_OFF   (UT_OFF + 1048576ull)       // uint [2 parity][2 dir][4 grp][2 half][128 u][8 bpair]
#define FL_OFF   (HB_OFF + 524288ull)        // uint flags[16]
#define WS_NEED  (FL_OFF + 256ull)

static __device__ __forceinline__ ushort f2bf(float f) {
  uint u = __float_as_uint(f);
  return (ushort)((u + 0x7fffu + ((u >> 16) & 1u)) >> 16);
}
static __device__ __forceinline__ float fsig(float x) {
  return 1.0f / (1.0f + __expf(-x));
}
static __device__ __forceinline__ float ftanh(float x) {
  return 1.0f - 2.0f / (__expf(2.0f * x) + 1.0f);
}
// select bf16 #p (0..3) out of a uint2 and widen to f32
static __device__ __forceinline__ float bfsel(uint2 v, int p) {
  uint w = (p & 2) ? v.y : v.x;
  uint bits = (p & 1) ? (w & 0xffff0000u) : (w << 16);
  return __uint_as_float(bits);
}

// ================= convert: x->bf16, W^T, U^T =================
__global__ __launch_bounds__(256) void k_convert(
    const float* __restrict__ x,
    const float* __restrict__ Wf, const float* __restrict__ Wb,
    const float* __restrict__ Uf, const float* __restrict__ Ub,
    ushort* __restrict__ xb, ushort* __restrict__ wt, ushort* __restrict__ ut)
{
  uint tid = blockIdx.x * 256u + threadIdx.x;
  if (tid < 2097152u) {            // x: 16.8M elems, 8 per thread
    uint base = tid * 8u;
    float4 a = *(const float4*)(x + base);
    float4 b = *(const float4*)(x + base + 4);
    uint4 o;
    o.x = (uint)f2bf(a.x) | ((uint)f2bf(a.y) << 16);
    o.y = (uint)f2bf(a.z) | ((uint)f2bf(a.w) << 16);
    o.z = (uint)f2bf(b.x) | ((uint)f2bf(b.y) << 16);
    o.w = (uint)f2bf(b.z) | ((uint)f2bf(b.w) << 16);
    *(uint4*)(xb + base) = o;
  } else {                         // transposes: 4 x 262144 elems
    uint e = tid - 2097152u;
    uint which = e >> 18;          // 0 Wf,1 Wb,2 Uf,3 Ub
    uint i = e & 262143u;
    uint n = i >> 8, k = i & 255u;
    const float* src = (which == 0) ? Wf : (which == 1) ? Wb : (which == 2) ? Uf : Ub;
    ushort v = f2bf(src[k * 1024u + n]);
    ushort* dst = (which < 2) ? (wt + which * 262144u) : (ut + (which - 2u) * 262144u);
    dst[n * 256u + k] = v;
  }
}

// ================= GEMM: xw[dir][b][col][t] = x @ W + bias =================
__global__ __launch_bounds__(256) void k_gemm(
    const ushort* __restrict__ xb, const ushort* __restrict__ wt,
    const float* __restrict__ biasF, const float* __restrict__ biasB,
    ushort* __restrict__ xw)
{
  const int dir = blockIdx.z;
  const ushort* W = wt + dir * 262144;
  const float* bias = dir ? biasB : biasF;
  const int m0 = blockIdx.x * 128;   // row block in (b,t) space; one b per block
  const int n0 = blockIdx.y * 128;
  const int tid = threadIdx.x;
  const int lane = tid & 63, wave = tid >> 6;
  const int l15 = lane & 15, l4 = lane >> 4;
  const int wr = wave >> 1, wc = wave & 1;

  __shared__ __align__(16) ushort lds[17408];   // stage A/B (10240) then trans (17408)
  ushort* As = lds;            // [128][40]
  ushort* Bs = lds + 5120;     // [128][40]

  f32x4 acc[4][4] = {};
  const int arow = tid >> 1, aseg = tid & 1;

  for (int kit = 0; kit < 8; ++kit) {
    int k0 = kit * 32;
    const ushort* sa = xb + (m0 + arow) * 256 + k0 + aseg * 16;
    uint4 a0 = *(const uint4*)sa;
    uint4 a1 = *(const uint4*)(sa + 8);
    const ushort* sb = W + (n0 + arow) * 256 + k0 + aseg * 16;
    uint4 b0 = *(const uint4*)sb;
    uint4 b1 = *(const uint4*)(sb + 8);
    *(uint4*)(As + arow * 40 + aseg * 16) = a0;
    *(uint4*)(As + arow * 40 + aseg * 16 + 8) = a1;
    *(uint4*)(Bs + arow * 40 + aseg * 16) = b0;
    *(uint4*)(Bs + arow * 40 + aseg * 16 + 8) = b1;
    __syncthreads();
    bf16x8 af[4], bfr[4];
#pragma unroll
    for (int m = 0; m < 4; ++m) af[m] = *(const bf16x8*)(As + (wr * 64 + m * 16 + l15) * 40 + l4 * 8);
#pragma unroll
    for (int n = 0; n < 4; ++n) bfr[n] = *(const bf16x8*)(Bs + (wc * 64 + n * 16 + l15) * 40 + l4 * 8);
#pragma unroll
    for (int m = 0; m < 4; ++m)
#pragma unroll
      for (int n = 0; n < 4; ++n)
        acc[m][n] = __builtin_amdgcn_mfma_f32_16x16x32_bf16(af[m], bfr[n], acc[m][n], 0, 0, 0);
    __syncthreads();
  }

  // epilogue: bias, bf16, transpose via LDS -> [col][t]
  float bv[4];
#pragma unroll
  for (int n = 0; n < 4; ++n) bv[n] = bias[n0 + wc * 64 + n * 16 + l15];
  uint* tl = (uint*)lds;    // [128][68] uints (t packed by 2)
#pragma unroll
  for (int m = 0; m < 4; ++m) {
    int tro2 = (wr * 64 + m * 16 + l4 * 4) >> 1;
#pragma unroll
    for (int n = 0; n < 4; ++n) {
      int col = wc * 64 + n * 16 + l15;
      uint v0 = (uint)f2bf(acc[m][n][0] + bv[n]) | ((uint)f2bf(acc[m][n][1] + bv[n]) << 16);
      uint v1 = (uint)f2bf(acc[m][n][2] + bv[n]) | ((uint)f2bf(acc[m][n][3] + bv[n]) << 16);
      tl[col * 68 + tro2] = v0;
      tl[col * 68 + tro2 + 1] = v1;
    }
  }
  __syncthreads();
  const int scol = tid >> 1, shalf = tid & 1;
  const int bb = m0 >> 10, t0 = (m0 & 1023) + shalf * 64;
  ushort* g = xw + ((uint)((dir * 64 + bb) * 1024 + (n0 + scol))) * 1024u + t0;
  const uint* s = tl + scol * 68 + shalf * 32;
#pragma unroll
  for (int j = 0; j < 8; ++j)
    *(uint4*)(g + j * 8) = *(const uint4*)(s + j * 4);
}

// ================= recurrence: 16 persistent blocks =================
// bid: half = bid>>3 (partner = bid^8, same-XCD heuristic), dir = (bid>>2)&1, grp = bid&3
__global__ __launch_bounds__(512, 2) void k_rec(
    const ushort* __restrict__ xw, const ushort* __restrict__ ut,
    const float* __restrict__ pif, const float* __restrict__ pff, const float* __restrict__ pof,
    const float* __restrict__ pib, const float* __restrict__ pfb, const float* __restrict__ pob,
    uint* hbuf, uint* flags, float* __restrict__ out)
{
  const int bid = blockIdx.x;
  const int half = bid >> 3;
  const int dir = (bid >> 2) & 1;
  const int grp = bid & 3;
  const int tid = threadIdx.x;
  const int lane = tid & 63, wave = tid >> 6;
  const int l15 = lane & 15, l4 = lane >> 4;
  const int u_loc = wave * 16 + l15;         // 0..127
  const int u_glb = half * 128 + u_loc;      // 0..255
  const int bg = grp * 16;

  const float* piP = dir ? pib : pif;
  const float* pfP = dir ? pfb : pff;
  const float* poP = dir ? pob : pof;
  const float ppi = piP[u_glb], ppf = pfP[u_glb], ppo = poP[u_glb];

  // U fragments in registers: breg[kt][nt] covers k=kt*32+l4*8..+8, col=nt*256+u_glb
  bf16x8 breg[8][4];
  const ushort* U = ut + dir * 262144;
#pragma unroll
  for (int nt = 0; nt < 4; ++nt) {
    const ushort* up = U + (nt * 256 + u_glb) * 256;
#pragma unroll
    for (int kt = 0; kt < 8; ++kt)
      breg[kt][nt] = *(const bf16x8*)(up + kt * 32 + l4 * 8);
  }

  __shared__ __align__(16) ushort hst[2][16][264];   // h staging, double-buffered by parity
  for (int i = tid; i < 2 * 16 * 264; i += 512) ((ushort*)hst)[i] = 0;

  uint* flag_own = flags + (dir * 4 + grp) * 2 + half;
  uint* flag_par = flags + (dir * 4 + grp) * 2 + (half ^ 1);
#define HBB(p, hf) (hbuf + (((((p)*2 + dir) * 4 + grp) * 2 + (hf)) * 1024))

  const ushort* xp = xw + ((uint)((dir * 64 + bg + l4 * 4) * 1024 + u_glb)) * 1024u;
  float* outp = out + ((uint)(bg + l4 * 4) * 1024u) * 512u + dir * 256 + u_glb;

  float cr[4] = {0.f, 0.f, 0.f, 0.f};
  __syncthreads();

  for (int t4 = 0; t4 < 1024; t4 += 4) {
    const int tload = dir ? (1020 - t4) : t4;
    uint2 xwb[4][4];
#pragma unroll
    for (int nt = 0; nt < 4; ++nt)
#pragma unroll
      for (int r = 0; r < 4; ++r)
        xwb[nt][r] = *(const uint2*)(xp + (uint)r * 1048576u + (uint)nt * 262144u + tload);

#pragma unroll
    for (int ph = 0; ph < 4; ++ph) {
      const int t = t4 + ph;
      const int rp = (t + 1) & 1;     // parity holding h_{t-1}
      if (t > 0 && tid < 256) {
        // wait for partner's step t (it stored h_{t-1})
        while (__hip_atomic_load(flag_par, __ATOMIC_ACQUIRE, __HIP_MEMORY_SCOPE_AGENT) < (uint)t) {
          __builtin_amdgcn_s_sleep(1);
        }
        // fetch partner half: hbuf words [u][bpair]; thread covers 4 units x 1 pair
        const uint* src = HBB(rp, half ^ 1);
        int u0 = (tid >> 3) * 4, pr = tid & 7;
        uint w0 = src[(u0 + 0) * 8 + pr];
        uint w1 = src[(u0 + 1) * 8 + pr];
        uint w2 = src[(u0 + 2) * 8 + pr];
        uint w3 = src[(u0 + 3) * 8 + pr];
        uint lo0 = (w0 & 0xffffu) | ((w1 & 0xffffu) << 16);
        uint lo1 = (w2 & 0xffffu) | ((w3 & 0xffffu) << 16);
        uint hi0 = (w0 >> 16) | (w1 & 0xffff0000u);
        uint hi1 = (w2 >> 16) | (w3 & 0xffff0000u);
        int uo = (half ^ 1) * 128 + u0;
        uint2 vlo; vlo.x = lo0; vlo.y = lo1;
        uint2 vhi; vhi.x = hi0; vhi.y = hi1;
        *(uint2*)&hst[rp][2 * pr][uo] = vlo;
        *(uint2*)&hst[rp][2 * pr + 1][uo] = vhi;
      }
      __syncthreads();

      f32x4 acc0 = {0.f, 0.f, 0.f, 0.f}, acc1 = acc0, acc2 = acc0, acc3 = acc0;
#pragma unroll
      for (int kt = 0; kt < 8; ++kt) {
        bf16x8 a = *(const bf16x8*)&hst[rp][l15][kt * 32 + l4 * 8];
        acc0 = __builtin_amdgcn_mfma_f32_16x16x32_bf16(a, breg[kt][0], acc0, 0, 0, 0);
        acc1 = __builtin_amdgcn_mfma_f32_16x16x32_bf16(a, breg[kt][1], acc1, 0, 0, 0);
        acc2 = __builtin_amdgcn_mfma_f32_16x16x32_bf16(a, breg[kt][2], acc2, 0, 0, 0);
        acc3 = __builtin_amdgcn_mfma_f32_16x16x32_bf16(a, breg[kt][3], acc3, 0, 0, 0);
      }

      const int phe = dir ? (3 - ph) : ph;
      const int tout = dir ? (1023 - t) : t;
      const int wp = t & 1;
      uint hw0 = 0, hw1 = 0;
#pragma unroll
      for (int r = 0; r < 4; ++r) {
        float cc = cr[r];
        float gi = acc0[r] + bfsel(xwb[0][r], phe);
        float gf = acc1[r] + bfsel(xwb[1][r], phe);
        float gg = acc2[r] + bfsel(xwb[2][r], phe);
        float go = acc3[r] + bfsel(xwb[3][r], phe);
        float iv = fsig(gi + ppi * cc);
        float fv = fsig(gf + ppf * cc);
        float cn = fv * cc + iv * ftanh(gg);
        float ov = fsig(go + ppo * cn);
        float hv = ov * ftanh(cn);
        cr[r] = cn;
        outp[(uint)r * 524288u + (uint)tout * 512u] = hv;
        ushort hb = f2bf(hv);
        hst[wp][l4 * 4 + r][u_glb] = hb;
        if (r == 0) hw0 = hb;
        else if (r == 1) hw0 |= ((uint)hb << 16);
        else if (r == 2) hw1 = hb;
        else hw1 |= ((uint)hb << 16);
      }
      {
        uint* dst = HBB(wp, half);
        dst[u_loc * 8 + l4 * 2] = hw0;
        dst[u_loc * 8 + l4 * 2 + 1] = hw1;
      }
      __syncthreads();   // drains vmcnt: all threads' hbuf stores at L2
      if (tid == 0)
        __hip_atomic_store(flag_own, (uint)(t + 1), __ATOMIC_RELEASE, __HIP_MEMORY_SCOPE_AGENT);
    }
  }
#undef HBB
}

// ================= dropout (exact JAX threefry) =================
#define TFR(r) { x0 += x1; x1 = (x1 << (r)) | (x1 >> (32 - (r))); x1 ^= x0; }
#define RND4A TFR(13) TFR(15) TFR(26) TFR(6)
#define RND4B TFR(17) TFR(29) TFR(16) TFR(24)

static __device__ __forceinline__ void threefry(uint c0, uint c1, uint& y0, uint& y1) {
  const uint k0 = 0u, k1 = 42u;
  const uint ks2 = k0 ^ k1 ^ 0x1BD11BDAu;
  uint x0 = c0 + k0, x1 = c1 + k1;
  RND4A x0 += k1;  x1 += ks2 + 1u;
  RND4B x0 += ks2; x1 += k0 + 2u;
  RND4A x0 += k0;  x1 += k1 + 3u;
  RND4B x0 += k1;  x1 += ks2 + 4u;
  RND4A x0 += ks2; x1 += k0 + 5u;
  y0 = x0; y1 = x1;
}

__global__ __launch_bounds__(256) void k_drop(float* out, uint n) {
#if DROP_VARIANT == 0
  uint i = blockIdx.x * 256u + threadIdx.x;   // pair index, i < n/2
  if (i < (n >> 1)) {
    uint y0, y1;
    threefry(i, i + (n >> 1), y0, y1);
    float a = out[i], b = out[i + (n >> 1)];
    out[i] = (y0 >> 31) ? 0.0f : a * 2.0f;
    out[i + (n >> 1)] = (y1 >> 31) ? 0.0f : b * 2.0f;
  }
#else
  uint i = blockIdx.x * 256u + threadIdx.x;
  if (i < n) {
    uint y0, y1;
    threefry(0u, i, y0, y1);
#if DROP_VARIANT == 2
    uint w = y0 ^ y1;
#else
    uint w = y0;
#endif
    float v = out[i];
    out[i] = (w >> 31) ? 0.0f : v * 2.0f;
  }
#endif
}

// ================= host =================
extern "C" void kernel_launch(void* const* d_in, const int* in_sizes, int n_in,
                              void* d_out, int out_size, void* d_ws, size_t ws_size,
                              hipStream_t stream)
{
  const float* x   = (const float*)d_in[0];
  const float* Wf  = (const float*)d_in[1];
  const float* Uf  = (const float*)d_in[2];
  const float* bf_ = (const float*)d_in[3];
  const float* pif = (const float*)d_in[4];
  const float* pff = (const float*)d_in[5];
  const float* pof = (const float*)d_in[6];
  const float* Wb  = (const float*)d_in[7];
  const float* Ub  = (const float*)d_in[8];
  const float* bb_ = (const float*)d_in[9];
  const float* pib = (const float*)d_in[10];
  const float* pfb = (const float*)d_in[11];
  const float* pob = (const float*)d_in[12];
  float* out = (float*)d_out;
  char* ws = (char*)d_ws;

  if (ws_size < WS_NEED) {
    // distinctive failure signal: zero output -> absmax == max|ref| (~1.155)
    hipMemsetAsync(d_out, 0, (size_t)out_size * 4, stream);
    return;
  }

  ushort* xwp = (ushort*)(ws + XW_OFF);
  ushort* xbp = (ushort*)(ws + XB_OFF);
  ushort* wtp = (ushort*)(ws + WT_OFF);
  ushort* utp = (ushort*)(ws + UT_OFF);
  uint* hbuf  = (uint*)(ws + HB_OFF);
  uint* flags = (uint*)(ws + FL_OFF);

  hipMemsetAsync(flags, 0, 64, stream);
  k_convert<<<12288, 256, 0, stream>>>(x, Wf, Wb, Uf, Ub, xbp, wtp, utp);
  k_gemm<<<dim3(512, 8, 2), 256, 0, stream>>>(xbp, wtp, bf_, bb_, xwp);
  k_rec<<<16, 512, 0, stream>>>(xwp, utp, pif, pff, pof, pib, pfb, pob, hbuf, flags, out);
#if DROP_VARIANT == 0
  k_drop<<<(out_size / 2 + 255) / 256, 256, 0, stream>>>(out, (uint)out_size);
#else
  k_drop<<<(out_size + 255) / 256, 256, 0, stream>>>(out, (uint)out_size);
#endif
}